// Round 3
// baseline (4977.033 us; speedup 1.0000x reference)
//
#include <hip/hip_runtime.h>
#include <cstdint>

// ---------------------------------------------------------------------------
// RNNres: emb -> LSTM(T=2048,B=64,NHID=256) -> ragged mean pool -> ResNet head
//   k0 : convert emb_w / W_ih to f16, bias = b_ih + b_hh
//   k1 : MFMA f16 GEMM gate table; stores PERMUTED layout:
//        xgtab[v*1024 + nt*64 + l16*4 + gate]  (4 gates adjacent per (v,n))
//   k0b: convert W_hh to f16 (into ws+0, aliasing dead emb16 region)
//   k2 : MFMA recurrence. 1 WG/batch, 512 thr. Per step one 16x16x32 MFMA
//        sweep computes all 1024 gates (A row0 = h, rows 1-15 = 0).
//        Weights: 40 frags/wave in regs (MFMA-native operands),
//        16 frags/wave LDS-resident (128KB), 8 frags/wave streamed from L2.
//        Each wave owns all 4 gates of its 32 hidden units -> elementwise
//        update fully in-lane, ONE barrier/step, h double-buffered.
//   k3 : tiny fp32 head
// ---------------------------------------------------------------------------

#define NTOKEN 50257
#define NINP 256
#define NHID 256
#define BB 64
#define TT 2048
#define NRES 10
#define NFC1 85
#define EPSV 1e-5f

typedef _Float16 f16;
typedef _Float16 f16x2 __attribute__((ext_vector_type(2)));
typedef _Float16 f16x4 __attribute__((ext_vector_type(4)));
typedef _Float16 f16x8 __attribute__((ext_vector_type(8)));
typedef float f32x4 __attribute__((ext_vector_type(4)));

static __device__ __forceinline__ float sigm(float x) { return 1.0f / (1.0f + __expf(-x)); }
static __device__ __forceinline__ float tanh_(float x) {
  float ax = fabsf(x);
  float e = __expf(-2.0f * ax);
  float t = (1.0f - e) / (1.0f + e);
  return x < 0.0f ? -t : t;
}

// ---------------------------------------------------------------- k0: convert
__global__ void k0_convert(const float* __restrict__ emb_w, const float* __restrict__ W_ih,
                           const float* __restrict__ b_ih, const float* __restrict__ b_hh,
                           f16* __restrict__ emb16, f16* __restrict__ wih16,
                           float* __restrict__ bias) {
  int64_t i = (int64_t)blockIdx.x * blockDim.x + threadIdx.x;
  if (i < (int64_t)NTOKEN * NINP) emb16[i] = (f16)emb_w[i];
  if (i < 4 * NHID * NINP) wih16[i] = (f16)W_ih[i];
  if (i < 4 * NHID) bias[i] = b_ih[i] + b_hh[i];
}

// ---------------------------------------------- k0b: W_hh -> f16 (after k1!)
__global__ void k0b_whh(const float* __restrict__ Whh, f16* __restrict__ whh16) {
  int i = blockIdx.x * 256 + threadIdx.x;
  if (i < 4 * NHID * NHID) whh16[i] = (f16)Whh[i];
}

// ------------------------------------------------- k1: gate-table f16 GEMM
__global__ __launch_bounds__(256) void k1_gemm(const f16* __restrict__ emb16,
                                               const f16* __restrict__ wih16,
                                               const float* __restrict__ bias,
                                               f16* __restrict__ xgtab) {
  __shared__ __align__(16) f16 a_lds[64][40];
  __shared__ __align__(16) f16 b_lds[256][40];
  const int mt = blockIdx.x;
  const int nt0 = blockIdx.y * 256;
  const int tid = threadIdx.x;
  const int lane = tid & 63;
  const int w = tid >> 6;
  const int quad = lane >> 4;
  const int l16 = lane & 15;

  f32x4 acc[16];
#pragma unroll
  for (int i = 0; i < 16; i++) acc[i] = (f32x4){0.f, 0.f, 0.f, 0.f};

  const int ar = tid >> 2;
  int av = mt * 64 + ar;
  if (av > NTOKEN - 1) av = NTOKEN - 1;
  const int ac = (tid & 3) * 8;

  for (int kb = 0; kb < 256; kb += 32) {
    *(uint4*)&a_lds[ar][ac] = *(const uint4*)&emb16[av * 256 + kb + ac];
    {
      const uint4* bs = (const uint4*)&wih16[(nt0 + tid) * 256 + kb];
      uint4* bd = (uint4*)&b_lds[tid][0];
      bd[0] = bs[0]; bd[1] = bs[1]; bd[2] = bs[2]; bd[3] = bs[3];
    }
    __syncthreads();
    f16x8 af = *(const f16x8*)&a_lds[w * 16 + l16][quad * 8];
#pragma unroll
    for (int nt = 0; nt < 16; nt++) {
      f16x8 bf = *(const f16x8*)&b_lds[nt * 16 + l16][quad * 8];
      acc[nt] = __builtin_amdgcn_mfma_f32_16x16x32_f16(af, bf, acc[nt], 0, 0, 0);
    }
    __syncthreads();
  }
  // permuted store: n = nt0 + nt*16 + l16 -> idx = nt*64 + l16*4 + gate
  // (gate = blockIdx.y since nt0 = gate*256)
#pragma unroll
  for (int nt = 0; nt < 16; nt++) {
#pragma unroll
    for (int rg = 0; rg < 4; rg++) {
      int v = mt * 64 + w * 16 + quad * 4 + rg;
      if (v < NTOKEN) {
        int n = nt0 + nt * 16 + l16;
        xgtab[v * 1024 + nt * 64 + l16 * 4 + blockIdx.y] = (f16)(acc[nt][rg] + bias[n]);
      }
    }
  }
}

// ------------------------------------------------------- k2: MFMA recurrence
// Wave w owns N-rows {g*256 + w*32 + hh*16 + l16 : g in 0..3, hh in 0..1}
// (8 N-tiles of 16x16x32). A operand: row 0 = h (lanes l16==0 carry it),
// rows 1-15 zero. C layout (harness-verified via k1): M-row = quad*4+reg,
// N-col = l16 -> valid outputs on quad==0 lanes, reg 0; all 4 gates of a
// hidden unit land in the SAME lane.
__global__ __attribute__((amdgpu_flat_work_group_size(512, 512), amdgpu_waves_per_eu(2, 2)))
void k2_rnn(const int* __restrict__ input, const float* __restrict__ hx0,
            const float* __restrict__ cx0, const int* __restrict__ seq_len,
            const f16* __restrict__ whh16, const f16* __restrict__ xgtab,
            float* __restrict__ feat, float* __restrict__ out_hx,
            float* __restrict__ out_cx) {
  __shared__ __align__(16) f16 wlds[8][16][64][8];  // 131072 B: ks 5,6 frags
  __shared__ __align__(16) f16 hbuf[2][256];        // 1024 B, double-buffered h

  const int b = blockIdx.x;
  const int tid = threadIdx.x;
  const int w = tid >> 6;
  const int lane = tid & 63;
  const int quad = lane >> 4;
  const int l16 = lane & 15;

  // per-lane element offset within a W_hh row-block: row (w*32+l16), col quad*8
  const int goff = (w * 32 + l16) * 256 + quad * 8;

  // ---- load resident weight frags from f16 table (k0b ran before us)
  f16x8 wreg[40];  // ks 0..4  (nt*5 + ks)
#pragma unroll
  for (int nt = 0; nt < 8; ++nt) {
    const int g = nt >> 1, hh = nt & 1;
    const f16* rp = whh16 + (g * 256 + hh * 16) * 256 + goff;
#pragma unroll
    for (int ks = 0; ks < 7; ++ks) {
      f16x8 fr = *(const f16x8*)(rp + ks * 32);
      if (ks < 5) wreg[nt * 5 + ks] = fr;
      else *(f16x8*)&wlds[w][(ks - 5) * 8 + nt][lane][0] = fr;
    }
  }

  float cst[2] = {0.f, 0.f}, pool2[2] = {0.f, 0.f}, hlast[2] = {0.f, 0.f};
  if (quad == 0) {
#pragma unroll
    for (int hh = 0; hh < 2; ++hh) {
      const int n = w * 32 + hh * 16 + l16;
      hbuf[0][n] = (f16)hx0[b * 256 + n];
      cst[hh] = cx0[b * 256 + n];
    }
  }
  const int L = seq_len[b];
  const int* tokp = input + b * TT;
  int tok1 = tokp[1];
  uint2 xgc_raw[2] = {{0u, 0u}, {0u, 0u}};
  uint2 xgn_raw[2] = {{0u, 0u}, {0u, 0u}};
  {
    const int tok0 = tokp[0];
    if (quad == 0) {
      const f16* xr = xgtab + (int64_t)tok0 * 1024 + w * 128 + l16 * 4;
      xgc_raw[0] = *(const uint2*)xr;
      xgc_raw[1] = *(const uint2*)(xr + 64);
    }
  }
  __syncthreads();

#pragma unroll 1
  for (int t = 0; t < TT; ++t) {
    const int cur = t & 1;

    // ks=7 frags: L2-resident stream (loop-invariant addresses)
    f16x8 g7[8];
#pragma unroll
    for (int nt = 0; nt < 8; ++nt) {
      const int g = nt >> 1, hh = nt & 1;
      g7[nt] = *(const f16x8*)(whh16 + (g * 256 + hh * 16) * 256 + 224 + goff);
    }

    // prefetch next-step token + xg (consumed at t+1 acc-init)
    const int tok2 = tokp[(t + 2 < TT) ? (t + 2) : (TT - 1)];
    if (quad == 0) {
      const f16* xr = xgtab + (int64_t)tok1 * 1024 + w * 128 + l16 * 4;
      xgn_raw[0] = *(const uint2*)xr;
      xgn_raw[1] = *(const uint2*)(xr + 64);
    }

    // acc init from xg (quad0 lanes carry C row 0; everything else 0)
    f32x4 acc[8];
#pragma unroll
    for (int nt = 0; nt < 8; ++nt) {
      const int g = nt >> 1, hh = nt & 1;
      float v = 0.f;
      if (quad == 0) v = (float)(__builtin_bit_cast(f16x4, xgc_raw[hh])[g]);
      acc[nt][0] = v; acc[nt][1] = 0.f; acc[nt][2] = 0.f; acc[nt][3] = 0.f;
    }

    // K-loop: 64 MFMA/wave, A row0 = h via masked 16B ds_read (4 lanes/wave)
#pragma unroll
    for (int ks = 0; ks < 8; ++ks) {
      f16x8 af;
#pragma unroll
      for (int z = 0; z < 8; ++z) af[z] = (f16)0;
      if (l16 == 0) af = *(const f16x8*)&hbuf[cur][ks * 32 + quad * 8];
#pragma unroll
      for (int nt = 0; nt < 8; ++nt) {
        f16x8 bf;
        if (ks < 5) bf = wreg[nt * 5 + ks];
        else if (ks < 7) bf = *(const f16x8*)&wlds[w][(ks - 5) * 8 + nt][lane][0];
        else bf = g7[nt];
        acc[nt] = __builtin_amdgcn_mfma_f32_16x16x32_f16(af, bf, acc[nt], 0, 0, 0);
      }
    }

    // elementwise: all 4 gates of (n = w*32+hh*16+l16) live in this lane
    if (quad == 0) {
#pragma unroll
      for (int hh = 0; hh < 2; ++hh) {
        const float iv = sigm(acc[0 + hh][0]);
        const float fv = sigm(acc[2 + hh][0]);
        const float gv = tanh_(acc[4 + hh][0]);
        const float ov = sigm(acc[6 + hh][0]);
        const float cc = fv * cst[hh] + iv * gv;
        cst[hh] = cc;
        const float hv = ov * tanh_(cc);
        hlast[hh] = hv;
        if (t < L) pool2[hh] += hv;
        hbuf[cur ^ 1][w * 32 + hh * 16 + l16] = (f16)hv;
      }
    }
    xgc_raw[0] = xgn_raw[0]; xgc_raw[1] = xgn_raw[1];
    tok1 = tok2;
    __syncthreads();
  }

  if (quad == 0) {
#pragma unroll
    for (int hh = 0; hh < 2; ++hh) {
      const int n = w * 32 + hh * 16 + l16;
      feat[b * 256 + n] = pool2[hh] / (float)L;
      out_hx[b * 256 + n] = hlast[hh];
      out_cx[b * 256 + n] = cst[hh];
    }
  }
}

// ------------------------------------------------------------- k3: head (fp32)
__global__ __launch_bounds__(256) void k3_head(const float* __restrict__ feat,
    const float* __restrict__ rfc1_w, const float* __restrict__ rfc1_b,
    const float* __restrict__ rbn_g, const float* __restrict__ rbn_b,
    const float* __restrict__ rbn_rm, const float* __restrict__ rbn_rv,
    const float* __restrict__ rfc2_w, const float* __restrict__ rfc2_b,
    const float* __restrict__ fc1_w, const float* __restrict__ fc1_b,
    const float* __restrict__ bn1_g, const float* __restrict__ bn1_b,
    const float* __restrict__ bn1_rm, const float* __restrict__ bn1_rv,
    const float* __restrict__ fc2_w, const float* __restrict__ fc2_b,
    float* __restrict__ logp) {
  __shared__ float f[256];
  __shared__ float f2[256];
  __shared__ float res[16];
  __shared__ float fcv[96];
  const int b = blockIdx.x, tid = threadIdx.x;
  const int wv = tid >> 6, lane = tid & 63;
  f[tid] = feat[b * 256 + tid];
  __syncthreads();
  for (int r = wv; r < NRES; r += 4) {
    float p = 0.f;
#pragma unroll
    for (int j0 = 0; j0 < 4; j0++) {
      int j = lane * 4 + j0;
      p += fmaxf(f[j], 0.f) * rfc1_w[r * 256 + j];
    }
    for (int off = 32; off > 0; off >>= 1) p += __shfl_down(p, off);
    if (lane == 0) {
      float x = p + rfc1_b[r];
      x = fmaxf(x, 0.f);
      x = (x - rbn_rm[r]) * rsqrtf(rbn_rv[r] + EPSV) * rbn_g[r] + rbn_b[r];
      res[r] = x;
    }
  }
  __syncthreads();
  {
    float s = rfc2_b[tid];
#pragma unroll
    for (int r = 0; r < NRES; r++) s += res[r] * rfc2_w[tid * NRES + r];
    f2[tid] = f[tid] + s;
  }
  __syncthreads();
  for (int o = wv; o < NFC1; o += 4) {
    float p = 0.f;
#pragma unroll
    for (int j0 = 0; j0 < 4; j0++) {
      int j = lane * 4 + j0;
      p += f2[j] * fc1_w[o * 256 + j];
    }
    for (int off = 32; off > 0; off >>= 1) p += __shfl_down(p, off);
    if (lane == 0) {
      float x = p + fc1_b[o];
      x = (x - bn1_rm[o]) * rsqrtf(bn1_rv[o] + EPSV) * bn1_g[o] + bn1_b[o];
      x = fmaxf(x, 0.01f * x);
      fcv[o] = x;
    }
  }
  __syncthreads();
  if (tid == 0) {
    float l0 = fc2_b[0], l1 = fc2_b[1];
    for (int o2 = 0; o2 < NFC1; o2++) {
      l0 += fcv[o2] * fc2_w[o2];
      l1 += fcv[o2] * fc2_w[NFC1 + o2];
    }
    float mx = fmaxf(l0, l1);
    float lse = mx + __logf(__expf(l0 - mx) + __expf(l1 - mx));
    logp[b * 2 + 0] = l0 - lse;
    logp[b * 2 + 1] = l1 - lse;
  }
}

// ---------------------------------------------------------------------------
extern "C" void kernel_launch(void* const* d_in, const int* in_sizes, int n_in,
                              void* d_out, int out_size, void* d_ws, size_t ws_size,
                              hipStream_t stream) {
  const int*   input  = (const int*)  d_in[0];
  const float* hx     = (const float*)d_in[1];
  const float* cx     = (const float*)d_in[2];
  const int*   seqlen = (const int*)  d_in[3];
  const float* emb_w  = (const float*)d_in[4];
  const float* W_ih   = (const float*)d_in[5];
  const float* W_hh   = (const float*)d_in[6];
  const float* b_ih   = (const float*)d_in[7];
  const float* b_hh   = (const float*)d_in[8];
  const float* rfc1_w = (const float*)d_in[9];
  const float* rfc1_b = (const float*)d_in[10];
  const float* rbn_g  = (const float*)d_in[11];
  const float* rbn_b  = (const float*)d_in[12];
  const float* rbn_rm = (const float*)d_in[13];
  const float* rbn_rv = (const float*)d_in[14];
  const float* rfc2_w = (const float*)d_in[15];
  const float* rfc2_b = (const float*)d_in[16];
  const float* fc1_w  = (const float*)d_in[17];
  const float* fc1_b  = (const float*)d_in[18];
  const float* bn1_g  = (const float*)d_in[19];
  const float* bn1_b  = (const float*)d_in[20];
  const float* bn1_rm = (const float*)d_in[21];
  const float* bn1_rv = (const float*)d_in[22];
  const float* fc2_w  = (const float*)d_in[23];
  const float* fc2_b  = (const float*)d_in[24];

  char* ws = (char*)d_ws;
  f16*   emb16 = (f16*)(ws);                 // 25,731,584 B (dead after k1)
  f16*   whh16 = (f16*)(ws);                 // 524,288 B, aliases emb16 (k0b after k1)
  f16*   wih16 = (f16*)(ws + 25731584);      //    524,288 B
  float* bias  = (float*)(ws + 26255872);    //      4,096 B
  f16*   xgtab = (f16*)(ws + 26259968);      // 102,926,336 B
  float* feat  = (float*)(ws + 129186304);   //     65,536 B

  float* out = (float*)d_out;   // [0,128): logp, [128,16512): hx_f, [16512,32896): cx_f

  k0_convert<<<dim3(NTOKEN), 256, 0, stream>>>(emb_w, W_ih, b_ih, b_hh, emb16, wih16, bias);
  k1_gemm<<<dim3((NTOKEN + 63) / 64, 4), 256, 0, stream>>>(emb16, wih16, bias, xgtab);
  k0b_whh<<<dim3((4 * NHID * NHID + 255) / 256), 256, 0, stream>>>(W_hh, whh16);
  k2_rnn<<<dim3(BB), 512, 0, stream>>>(input, hx, cx, seqlen, whh16, xgtab, feat,
                                       out + 128, out + 128 + BB * NHID);
  k3_head<<<dim3(BB), 256, 0, stream>>>(feat, rfc1_w, rfc1_b, rbn_g, rbn_b, rbn_rm, rbn_rv,
                                        rfc2_w, rfc2_b, fc1_w, fc1_b, bn1_g, bn1_b, bn1_rm,
                                        bn1_rv, fc2_w, fc2_b, out);
}

// Round 4
// 4821.867 us; speedup vs baseline: 1.0322x; 1.0322x over previous
//
#include <hip/hip_runtime.h>
#include <cstdint>

// ---------------------------------------------------------------------------
// RNNres: emb -> LSTM(T=2048,B=64,NHID=256) -> ragged mean pool -> ResNet head
//   k0 : convert emb_w / W_ih to f16, bias = b_ih + b_hh
//   k1 : MFMA f16 GEMM gate table; stores PERMUTED layout:
//        xgtab[v*1024 + nt*64 + l16*4 + gate]  (4 gates adjacent per (v,n))
//   k0b: convert W_hh to f16 (into ws+0, aliasing dead emb16 region)
//   k2 : MFMA recurrence. 1 WG/batch, 512 thr. Per step one 16x16x32 MFMA
//        sweep computes all 1024 gates (A row0 = h, rows 1-15 = 0).
//        Weight frags (64/wave) by storage class, EXACT residency:
//          f = ks*8+nt;  f<36 regs | 36<=f<55 LDS (152KB) | f>=55 L2 stream
//        Stream (9 frags) issued at step-top, consumed by the LAST 9 MFMAs.
//        xg added POST-MFMA (frees prefetch regs; load self-hides under MFMA).
//        ONE barrier/step, h double-buffered.
//   k3 : tiny fp32 head
// ---------------------------------------------------------------------------

#define NTOKEN 50257
#define NINP 256
#define NHID 256
#define BB 64
#define TT 2048
#define NRES 10
#define NFC1 85
#define EPSV 1e-5f

#define NREGF 36   // frags f < NREGF in registers
#define NLDSF 19   // frags NREGF <= f < NREGF+NLDSF in LDS
#define FSTRM (NREGF + NLDSF)   // 55: frags f >= FSTRM streamed from L2
#define NSTRM (64 - FSTRM)      // 9

typedef _Float16 f16;
typedef _Float16 f16x2 __attribute__((ext_vector_type(2)));
typedef _Float16 f16x4 __attribute__((ext_vector_type(4)));
typedef _Float16 f16x8 __attribute__((ext_vector_type(8)));
typedef float f32x4 __attribute__((ext_vector_type(4)));

static __device__ __forceinline__ float sigm(float x) { return 1.0f / (1.0f + __expf(-x)); }
static __device__ __forceinline__ float tanh_(float x) {
  float ax = fabsf(x);
  float e = __expf(-2.0f * ax);
  float t = (1.0f - e) / (1.0f + e);
  return x < 0.0f ? -t : t;
}

// ---------------------------------------------------------------- k0: convert
__global__ void k0_convert(const float* __restrict__ emb_w, const float* __restrict__ W_ih,
                           const float* __restrict__ b_ih, const float* __restrict__ b_hh,
                           f16* __restrict__ emb16, f16* __restrict__ wih16,
                           float* __restrict__ bias) {
  int64_t i = (int64_t)blockIdx.x * blockDim.x + threadIdx.x;
  if (i < (int64_t)NTOKEN * NINP) emb16[i] = (f16)emb_w[i];
  if (i < 4 * NHID * NINP) wih16[i] = (f16)W_ih[i];
  if (i < 4 * NHID) bias[i] = b_ih[i] + b_hh[i];
}

// ---------------------------------------------- k0b: W_hh -> f16 (after k1!)
__global__ void k0b_whh(const float* __restrict__ Whh, f16* __restrict__ whh16) {
  int i = blockIdx.x * 256 + threadIdx.x;
  if (i < 4 * NHID * NHID) whh16[i] = (f16)Whh[i];
}

// ------------------------------------------------- k1: gate-table f16 GEMM
__global__ __launch_bounds__(256) void k1_gemm(const f16* __restrict__ emb16,
                                               const f16* __restrict__ wih16,
                                               const float* __restrict__ bias,
                                               f16* __restrict__ xgtab) {
  __shared__ __align__(16) f16 a_lds[64][40];
  __shared__ __align__(16) f16 b_lds[256][40];
  const int mt = blockIdx.x;
  const int nt0 = blockIdx.y * 256;
  const int tid = threadIdx.x;
  const int lane = tid & 63;
  const int w = tid >> 6;
  const int quad = lane >> 4;
  const int l16 = lane & 15;

  f32x4 acc[16];
#pragma unroll
  for (int i = 0; i < 16; i++) acc[i] = (f32x4){0.f, 0.f, 0.f, 0.f};

  const int ar = tid >> 2;
  int av = mt * 64 + ar;
  if (av > NTOKEN - 1) av = NTOKEN - 1;
  const int ac = (tid & 3) * 8;

  for (int kb = 0; kb < 256; kb += 32) {
    *(uint4*)&a_lds[ar][ac] = *(const uint4*)&emb16[av * 256 + kb + ac];
    {
      const uint4* bs = (const uint4*)&wih16[(nt0 + tid) * 256 + kb];
      uint4* bd = (uint4*)&b_lds[tid][0];
      bd[0] = bs[0]; bd[1] = bs[1]; bd[2] = bs[2]; bd[3] = bs[3];
    }
    __syncthreads();
    f16x8 af = *(const f16x8*)&a_lds[w * 16 + l16][quad * 8];
#pragma unroll
    for (int nt = 0; nt < 16; nt++) {
      f16x8 bf = *(const f16x8*)&b_lds[nt * 16 + l16][quad * 8];
      acc[nt] = __builtin_amdgcn_mfma_f32_16x16x32_f16(af, bf, acc[nt], 0, 0, 0);
    }
    __syncthreads();
  }
  // permuted store: n = nt0 + nt*16 + l16 -> idx = nt*64 + l16*4 + gate
  // (gate = blockIdx.y since nt0 = gate*256)
#pragma unroll
  for (int nt = 0; nt < 16; nt++) {
#pragma unroll
    for (int rg = 0; rg < 4; rg++) {
      int v = mt * 64 + w * 16 + quad * 4 + rg;
      if (v < NTOKEN) {
        int n = nt0 + nt * 16 + l16;
        xgtab[v * 1024 + nt * 64 + l16 * 4 + blockIdx.y] = (f16)(acc[nt][rg] + bias[n]);
      }
    }
  }
}

// ------------------------------------------------------- k2: MFMA recurrence
// Wave w owns N-rows {g*256 + w*32 + hh*16 + l16 : g in 0..3, hh in 0..1}
// (8 N-tiles, nt = g*2+hh). A operand: row 0 = h (lanes l16==0 carry it),
// rows 1-15 zero. C layout (harness-verified via k1): M-row = quad*4+reg,
// N-col = l16 -> valid outputs on quad==0 lanes, reg 0; all 4 gates of a
// hidden unit land in the SAME lane.
__global__ __attribute__((amdgpu_flat_work_group_size(512, 512), amdgpu_waves_per_eu(2, 2)))
void k2_rnn(const int* __restrict__ input, const float* __restrict__ hx0,
            const float* __restrict__ cx0, const int* __restrict__ seq_len,
            const f16* __restrict__ whh16, const f16* __restrict__ xgtab,
            float* __restrict__ feat, float* __restrict__ out_hx,
            float* __restrict__ out_cx) {
  __shared__ __align__(16) f16 wlds[8][NLDSF][64][8];  // 155,648 B
  __shared__ __align__(16) f16 hbuf[2][256];           // 1,024 B

  const int b = blockIdx.x;
  const int tid = threadIdx.x;
  const int w = tid >> 6;
  const int lane = tid & 63;
  const int quad = lane >> 4;
  const int l16 = lane & 15;

  // per-lane element offset within a W_hh row-block: row (w*32+l16), col quad*8
  const int goff = (w * 32 + l16) * 256 + quad * 8;

  // ---- load resident weight frags (f = ks*8 + nt; nt = g*2+hh)
  f16x8 wreg[NREGF];
#pragma unroll
  for (int ks = 0; ks < 8; ++ks) {
#pragma unroll
    for (int nt = 0; nt < 8; ++nt) {
      const int f = ks * 8 + nt;
      if (f >= FSTRM) continue;  // streamed per-step
      const int g = nt >> 1, hh = nt & 1;
      f16x8 fr = *(const f16x8*)(whh16 + (g * 256 + hh * 16) * 256 + ks * 32 + goff);
      if (f < NREGF) wreg[f] = fr;
      else *(f16x8*)&wlds[w][f - NREGF][lane][0] = fr;
    }
  }

  float cst[2] = {0.f, 0.f}, pool2[2] = {0.f, 0.f}, hlast[2] = {0.f, 0.f};
  if (quad == 0) {
#pragma unroll
    for (int hh = 0; hh < 2; ++hh) {
      const int n = w * 32 + hh * 16 + l16;
      hbuf[0][n] = (f16)hx0[b * 256 + n];
      cst[hh] = cx0[b * 256 + n];
    }
  }
  const int L = seq_len[b];
  const int* tokp = input + b * TT;
  int tok_cur = tokp[0];
  __syncthreads();

#pragma unroll 1
  for (int t = 0; t < TT; ++t) {
    const int cur = t & 1;

    // ---- stream frags (f >= FSTRM): issued now, consumed by the LAST MFMAs
    f16x8 st[NSTRM];
#pragma unroll
    for (int q = 0; q < NSTRM; ++q) {
      const int f = FSTRM + q, ks = f >> 3, nt = f & 7;
      const int g = nt >> 1, hh = nt & 1;
      st[q] = *(const f16x8*)(whh16 + (g * 256 + hh * 16) * 256 + ks * 32 + goff);
    }

    // ---- xg gather for THIS step (consumed post-MFMA => latency self-hides)
    uint2 xg0 = {0u, 0u}, xg1 = {0u, 0u};
    if (quad == 0) {
      const f16* xr = xgtab + (int64_t)tok_cur * 1024 + w * 128 + l16 * 4;
      xg0 = *(const uint2*)xr;
      xg1 = *(const uint2*)(xr + 64);
    }
    const int tok_nx = tokp[(t + 1 < TT) ? (t + 1) : (TT - 1)];

    // ---- MFMA sweep, acc starts at 0 (xg added in elementwise phase)
    f32x4 acc[8];
#pragma unroll
    for (int nt = 0; nt < 8; ++nt) acc[nt] = (f32x4){0.f, 0.f, 0.f, 0.f};

#pragma unroll
    for (int ks = 0; ks < 8; ++ks) {
      f16x8 af;
#pragma unroll
      for (int z = 0; z < 8; ++z) af[z] = (f16)0;
      if (l16 == 0) af = *(const f16x8*)&hbuf[cur][ks * 32 + quad * 8];
#pragma unroll
      for (int nt = 0; nt < 8; ++nt) {
        const int f = ks * 8 + nt;
        f16x8 bf;
        if (f < NREGF) bf = wreg[f];
        else if (f < FSTRM) bf = *(const f16x8*)&wlds[w][f - NREGF][lane][0];
        else bf = st[f - FSTRM];
        acc[nt] = __builtin_amdgcn_mfma_f32_16x16x32_f16(af, bf, acc[nt], 0, 0, 0);
      }
    }

    // ---- elementwise: all 4 gates of (n = w*32+hh*16+l16) live in this lane
    if (quad == 0) {
      const f16x4 xa = __builtin_bit_cast(f16x4, xg0);
      const f16x4 xb = __builtin_bit_cast(f16x4, xg1);
#pragma unroll
      for (int hh = 0; hh < 2; ++hh) {
        const f16x4 xv = hh ? xb : xa;
        const float iv = sigm(acc[0 + hh][0] + (float)xv[0]);
        const float fv = sigm(acc[2 + hh][0] + (float)xv[1]);
        const float gv = tanh_(acc[4 + hh][0] + (float)xv[2]);
        const float ov = sigm(acc[6 + hh][0] + (float)xv[3]);
        const float cc = fv * cst[hh] + iv * gv;
        cst[hh] = cc;
        const float hv = ov * tanh_(cc);
        hlast[hh] = hv;
        if (t < L) pool2[hh] += hv;
        hbuf[cur ^ 1][w * 32 + hh * 16 + l16] = (f16)hv;
      }
    }
    tok_cur = tok_nx;
    __syncthreads();
  }

  if (quad == 0) {
#pragma unroll
    for (int hh = 0; hh < 2; ++hh) {
      const int n = w * 32 + hh * 16 + l16;
      feat[b * 256 + n] = pool2[hh] / (float)L;
      out_hx[b * 256 + n] = hlast[hh];
      out_cx[b * 256 + n] = cst[hh];
    }
  }
}

// ------------------------------------------------------------- k3: head (fp32)
__global__ __launch_bounds__(256) void k3_head(const float* __restrict__ feat,
    const float* __restrict__ rfc1_w, const float* __restrict__ rfc1_b,
    const float* __restrict__ rbn_g, const float* __restrict__ rbn_b,
    const float* __restrict__ rbn_rm, const float* __restrict__ rbn_rv,
    const float* __restrict__ rfc2_w, const float* __restrict__ rfc2_b,
    const float* __restrict__ fc1_w, const float* __restrict__ fc1_b,
    const float* __restrict__ bn1_g, const float* __restrict__ bn1_b,
    const float* __restrict__ bn1_rm, const float* __restrict__ bn1_rv,
    const float* __restrict__ fc2_w, const float* __restrict__ fc2_b,
    float* __restrict__ logp) {
  __shared__ float f[256];
  __shared__ float f2[256];
  __shared__ float res[16];
  __shared__ float fcv[96];
  const int b = blockIdx.x, tid = threadIdx.x;
  const int wv = tid >> 6, lane = tid & 63;
  f[tid] = feat[b * 256 + tid];
  __syncthreads();
  for (int r = wv; r < NRES; r += 4) {
    float p = 0.f;
#pragma unroll
    for (int j0 = 0; j0 < 4; j0++) {
      int j = lane * 4 + j0;
      p += fmaxf(f[j], 0.f) * rfc1_w[r * 256 + j];
    }
    for (int off = 32; off > 0; off >>= 1) p += __shfl_down(p, off);
    if (lane == 0) {
      float x = p + rfc1_b[r];
      x = fmaxf(x, 0.f);
      x = (x - rbn_rm[r]) * rsqrtf(rbn_rv[r] + EPSV) * rbn_g[r] + rbn_b[r];
      res[r] = x;
    }
  }
  __syncthreads();
  {
    float s = rfc2_b[tid];
#pragma unroll
    for (int r = 0; r < NRES; r++) s += res[r] * rfc2_w[tid * NRES + r];
    f2[tid] = f[tid] + s;
  }
  __syncthreads();
  for (int o = wv; o < NFC1; o += 4) {
    float p = 0.f;
#pragma unroll
    for (int j0 = 0; j0 < 4; j0++) {
      int j = lane * 4 + j0;
      p += f2[j] * fc1_w[o * 256 + j];
    }
    for (int off = 32; off > 0; off >>= 1) p += __shfl_down(p, off);
    if (lane == 0) {
      float x = p + fc1_b[o];
      x = (x - bn1_rm[o]) * rsqrtf(bn1_rv[o] + EPSV) * bn1_g[o] + bn1_b[o];
      x = fmaxf(x, 0.01f * x);
      fcv[o] = x;
    }
  }
  __syncthreads();
  if (tid == 0) {
    float l0 = fc2_b[0], l1 = fc2_b[1];
    for (int o2 = 0; o2 < NFC1; o2++) {
      l0 += fcv[o2] * fc2_w[o2];
      l1 += fcv[o2] * fc2_w[NFC1 + o2];
    }
    float mx = fmaxf(l0, l1);
    float lse = mx + __logf(__expf(l0 - mx) + __expf(l1 - mx));
    logp[b * 2 + 0] = l0 - lse;
    logp[b * 2 + 1] = l1 - lse;
  }
}

// ---------------------------------------------------------------------------
extern "C" void kernel_launch(void* const* d_in, const int* in_sizes, int n_in,
                              void* d_out, int out_size, void* d_ws, size_t ws_size,
                              hipStream_t stream) {
  const int*   input  = (const int*)  d_in[0];
  const float* hx     = (const float*)d_in[1];
  const float* cx     = (const float*)d_in[2];
  const int*   seqlen = (const int*)  d_in[3];
  const float* emb_w  = (const float*)d_in[4];
  const float* W_ih   = (const float*)d_in[5];
  const float* W_hh   = (const float*)d_in[6];
  const float* b_ih   = (const float*)d_in[7];
  const float* b_hh   = (const float*)d_in[8];
  const float* rfc1_w = (const float*)d_in[9];
  const float* rfc1_b = (const float*)d_in[10];
  const float* rbn_g  = (const float*)d_in[11];
  const float* rbn_b  = (const float*)d_in[12];
  const float* rbn_rm = (const float*)d_in[13];
  const float* rbn_rv = (const float*)d_in[14];
  const float* rfc2_w = (const float*)d_in[15];
  const float* rfc2_b = (const float*)d_in[16];
  const float* fc1_w  = (const float*)d_in[17];
  const float* fc1_b  = (const float*)d_in[18];
  const float* bn1_g  = (const float*)d_in[19];
  const float* bn1_b  = (const float*)d_in[20];
  const float* bn1_rm = (const float*)d_in[21];
  const float* bn1_rv = (const float*)d_in[22];
  const float* fc2_w  = (const float*)d_in[23];
  const float* fc2_b  = (const float*)d_in[24];

  char* ws = (char*)d_ws;
  f16*   emb16 = (f16*)(ws);                 // 25,731,584 B (dead after k1)
  f16*   whh16 = (f16*)(ws);                 // 524,288 B, aliases emb16 (k0b after k1)
  f16*   wih16 = (f16*)(ws + 25731584);      //    524,288 B
  float* bias  = (float*)(ws + 26255872);    //      4,096 B
  f16*   xgtab = (f16*)(ws + 26259968);      // 102,926,336 B
  float* feat  = (float*)(ws + 129186304);   //     65,536 B

  float* out = (float*)d_out;   // [0,128): logp, [128,16512): hx_f, [16512,32896): cx_f

  k0_convert<<<dim3(NTOKEN), 256, 0, stream>>>(emb_w, W_ih, b_ih, b_hh, emb16, wih16, bias);
  k1_gemm<<<dim3((NTOKEN + 63) / 64, 4), 256, 0, stream>>>(emb16, wih16, bias, xgtab);
  k0b_whh<<<dim3((4 * NHID * NHID + 255) / 256), 256, 0, stream>>>(W_hh, whh16);
  k2_rnn<<<dim3(BB), 512, 0, stream>>>(input, hx, cx, seqlen, whh16, xgtab, feat,
                                       out + 128, out + 128 + BB * NHID);
  k3_head<<<dim3(BB), 256, 0, stream>>>(feat, rfc1_w, rfc1_b, rbn_g, rbn_b, rbn_rm, rbn_rv,
                                        rfc2_w, rfc2_b, fc1_w, fc1_b, bn1_g, bn1_b, bn1_rm,
                                        bn1_rv, fc2_w, fc2_b, out);
}

// Round 5
// 4687.456 us; speedup vs baseline: 1.0618x; 1.0287x over previous
//
#include <hip/hip_runtime.h>
#include <cstdint>

// ---------------------------------------------------------------------------
// RNNres: emb -> LSTM(T=2048,B=64,NHID=256) -> ragged mean pool -> ResNet head
//   k0 : convert emb_w / W_ih to f16, bias = b_ih + b_hh
//   k1 : MFMA f16 GEMM gate table; stores PERMUTED layout:
//        xgtab[v*1024 + 4*u + g]  (4 gates adjacent per (v,u))
//   k2 : persistent fdot2 recurrence, 1 WG/batch, 1024 thr (16 waves,
//        4 waves/SIMD). Thread owns ONE gate row: row = (tid&3)*256+(tid>>2)
//        -> the 4 gates of unit u are in ADJACENT LANES (shfl exchange, no
//        LDS round-trip). Weights: 90 half2 pairs in regs (fits 128-VGPR
//        budget at 4 waves/EU — v2-v4 all spilled), 38 pairs in LDS (152KB).
//        xg load coalesced (xgtab[tok*1024+tid]) and prefetched 1 step ahead.
//        ONE barrier/step, h double-buffered, h broadcast via same-addr b128.
//   k3 : tiny fp32 head
// ---------------------------------------------------------------------------

#define NTOKEN 50257
#define NINP 256
#define NHID 256
#define BB 64
#define TT 2048
#define NRES 10
#define NFC1 85
#define EPSV 1e-5f

#define RK 90                    // half2 pairs per thread kept in registers
#define LSLOT ((128 - RK) / 2)   // 19 uint2 LDS slots per thread

typedef _Float16 f16;
typedef _Float16 f16x2 __attribute__((ext_vector_type(2)));
typedef _Float16 f16x8 __attribute__((ext_vector_type(8)));
typedef float f32x4 __attribute__((ext_vector_type(4)));

static __device__ __forceinline__ float sigm(float x) { return 1.0f / (1.0f + __expf(-x)); }
static __device__ __forceinline__ float tanh_(float x) {
  float ax = fabsf(x);
  float e = __expf(-2.0f * ax);
  float t = (1.0f - e) / (1.0f + e);
  return x < 0.0f ? -t : t;
}

static __device__ __forceinline__ float fdot2(f16x2 a, f16x2 b, float c) {
#if __has_builtin(__builtin_amdgcn_fdot2)
  return __builtin_amdgcn_fdot2(a, b, c, false);
#else
  return c + (float)a[0] * (float)b[0] + (float)a[1] * (float)b[1];
#endif
}

// ---------------------------------------------------------------- k0: convert
__global__ void k0_convert(const float* __restrict__ emb_w, const float* __restrict__ W_ih,
                           const float* __restrict__ b_ih, const float* __restrict__ b_hh,
                           f16* __restrict__ emb16, f16* __restrict__ wih16,
                           float* __restrict__ bias) {
  int64_t i = (int64_t)blockIdx.x * blockDim.x + threadIdx.x;
  if (i < (int64_t)NTOKEN * NINP) emb16[i] = (f16)emb_w[i];
  if (i < 4 * NHID * NINP) wih16[i] = (f16)W_ih[i];
  if (i < 4 * NHID) bias[i] = b_ih[i] + b_hh[i];
}

// ------------------------------------------------- k1: gate-table f16 GEMM
__global__ __launch_bounds__(256) void k1_gemm(const f16* __restrict__ emb16,
                                               const f16* __restrict__ wih16,
                                               const float* __restrict__ bias,
                                               f16* __restrict__ xgtab) {
  __shared__ __align__(16) f16 a_lds[64][40];
  __shared__ __align__(16) f16 b_lds[256][40];
  const int mt = blockIdx.x;
  const int nt0 = blockIdx.y * 256;
  const int tid = threadIdx.x;
  const int lane = tid & 63;
  const int w = tid >> 6;
  const int quad = lane >> 4;
  const int l16 = lane & 15;

  f32x4 acc[16];
#pragma unroll
  for (int i = 0; i < 16; i++) acc[i] = (f32x4){0.f, 0.f, 0.f, 0.f};

  const int ar = tid >> 2;
  int av = mt * 64 + ar;
  if (av > NTOKEN - 1) av = NTOKEN - 1;
  const int ac = (tid & 3) * 8;

  for (int kb = 0; kb < 256; kb += 32) {
    *(uint4*)&a_lds[ar][ac] = *(const uint4*)&emb16[av * 256 + kb + ac];
    {
      const uint4* bs = (const uint4*)&wih16[(nt0 + tid) * 256 + kb];
      uint4* bd = (uint4*)&b_lds[tid][0];
      bd[0] = bs[0]; bd[1] = bs[1]; bd[2] = bs[2]; bd[3] = bs[3];
    }
    __syncthreads();
    f16x8 af = *(const f16x8*)&a_lds[w * 16 + l16][quad * 8];
#pragma unroll
    for (int nt = 0; nt < 16; nt++) {
      f16x8 bf = *(const f16x8*)&b_lds[nt * 16 + l16][quad * 8];
      acc[nt] = __builtin_amdgcn_mfma_f32_16x16x32_f16(af, bf, acc[nt], 0, 0, 0);
    }
    __syncthreads();
  }
  // permuted store: unit-in-chunk u = nt*16 + l16, gate = blockIdx.y
  // -> idx = nt*64 + l16*4 + gate == 4*u + gate
#pragma unroll
  for (int nt = 0; nt < 16; nt++) {
#pragma unroll
    for (int rg = 0; rg < 4; rg++) {
      int v = mt * 64 + w * 16 + quad * 4 + rg;
      if (v < NTOKEN) {
        int n = nt0 + nt * 16 + l16;
        xgtab[v * 1024 + nt * 64 + l16 * 4 + blockIdx.y] = (f16)(acc[nt][rg] + bias[n]);
      }
    }
  }
}

// ------------------------------------------------------- k2: LSTM recurrence
// 1024 threads: g = tid&3 (gate: 0=i,1=f,2=cell,3=o), u = tid>>2 (unit).
// Thread owns W_hh row g*256+u. Gates of unit u live in lanes 4k..4k+3 of the
// same wave -> shfl_down exchange. xg read: xgtab[tok*1024 + tid] (coalesced).
__global__ __launch_bounds__(1024, 4)
void k2_rnn(const int* __restrict__ input, const float* __restrict__ hx0,
            const float* __restrict__ cx0, const int* __restrict__ seq_len,
            const float* __restrict__ Whh, const f16* __restrict__ xgtab,
            float* __restrict__ feat, float* __restrict__ out_hx,
            float* __restrict__ out_cx) {
  __shared__ uint2 lw2[LSLOT * 1024];            // 155,648 B
  __shared__ __align__(16) f16 hpak[2][NHID];    // 1,024 B

  const int b = blockIdx.x;
  const int tid = threadIdx.x;
  const int g = tid & 3;
  const int u = tid >> 2;
  const int row = g * 256 + u;

  // ---- load + pack this thread's W_hh row (fp32 -> half2), split regs/LDS
  unsigned int wr[RK];
  unsigned int pend = 0;
#pragma unroll
  for (int m = 0; m < 128; ++m) {
    float2 a = *(const float2*)&Whh[row * 256 + 2 * m];
    f16x2 p; p[0] = (f16)a.x; p[1] = (f16)a.y;
    unsigned int ua = __builtin_bit_cast(unsigned int, p);
    if (m < RK) wr[m] = ua;
    else if (((m - RK) & 1) == 0) pend = ua;
    else lw2[((m - RK) >> 1) * 1024 + tid] = make_uint2(pend, ua);
  }

  float c = 0.f, pool = 0.f, hlast = 0.f;
  if (g == 0) {
    hpak[0][u] = (f16)hx0[b * NHID + u];
    c = cx0[b * NHID + u];
  }
  const int L = seq_len[b];
  const int* tokp = input + b * TT;
  int toknx = tokp[1];
  f16 xgc = xgtab[(int64_t)tokp[0] * 1024 + tid];
  __syncthreads();

#pragma unroll 1
  for (int t = 0; t < TT; ++t) {
    const int cur = t & 1;

    // prefetch next-step xg (consumed at t+1 => latency fully hidden)
    f16 xgn = xgtab[(int64_t)toknx * 1024 + tid];
    const int tok2 = tokp[(t + 2 < TT) ? (t + 2) : (TT - 1)];

    float acc = (float)xgc;
    const uint4* hp = (const uint4*)hpak[cur];
    uint4 hC = hp[0];
    uint4 hN = hp[1];
    uint2 lwv = {0u, 0u};
#pragma unroll
    for (int mb = 0; mb < 32; ++mb) {
      uint4 h4 = hC;  // same-address ds_read_b128 across wave -> broadcast
      hC = hN;
      if (mb < 30) hN = hp[mb + 2];
#pragma unroll
      for (int j = 0; j < 4; ++j) {
        const int m = mb * 4 + j;
        unsigned int hu = (j == 0) ? h4.x : (j == 1) ? h4.y : (j == 2) ? h4.z : h4.w;
        f16x2 hh = __builtin_bit_cast(f16x2, hu);
        unsigned int wu;
        if (m < RK) {
          wu = wr[m];
        } else {
          const int q = m - RK;
          if ((q & 1) == 0) {
            lwv = lw2[(q >> 1) * 1024 + tid];  // ds_read_b64, stride-1
            wu = lwv.x;
          } else {
            wu = lwv.y;
          }
        }
        acc = fdot2(__builtin_bit_cast(f16x2, wu), hh, acc);
      }
    }

    // ---- per-gate activation on ALL lanes, then 4-lane exchange via shfl
    float sv = sigm(acc);
    float act = (g == 2) ? tanh_(acc) : sv;
    float fch = __shfl_down(act, 1);
    float gch = __shfl_down(act, 2);
    float och = __shfl_down(act, 3);
    if (g == 0) {
      c = fch * c + act * gch;       // act = sigm(i) on g==0 lanes
      hlast = och * tanh_(c);
      if (t < L) pool += hlast;
      hpak[cur ^ 1][u] = (f16)hlast;
    }
    xgc = xgn;
    toknx = tok2;
    __syncthreads();
  }

  if (g == 0) {
    feat[b * NHID + u] = pool / (float)L;
    out_hx[b * NHID + u] = hlast;
    out_cx[b * NHID + u] = c;
  }
}

// ------------------------------------------------------------- k3: head (fp32)
__global__ __launch_bounds__(256) void k3_head(const float* __restrict__ feat,
    const float* __restrict__ rfc1_w, const float* __restrict__ rfc1_b,
    const float* __restrict__ rbn_g, const float* __restrict__ rbn_b,
    const float* __restrict__ rbn_rm, const float* __restrict__ rbn_rv,
    const float* __restrict__ rfc2_w, const float* __restrict__ rfc2_b,
    const float* __restrict__ fc1_w, const float* __restrict__ fc1_b,
    const float* __restrict__ bn1_g, const float* __restrict__ bn1_b,
    const float* __restrict__ bn1_rm, const float* __restrict__ bn1_rv,
    const float* __restrict__ fc2_w, const float* __restrict__ fc2_b,
    float* __restrict__ logp) {
  __shared__ float f[256];
  __shared__ float f2[256];
  __shared__ float res[16];
  __shared__ float fcv[96];
  const int b = blockIdx.x, tid = threadIdx.x;
  const int wv = tid >> 6, lane = tid & 63;
  f[tid] = feat[b * 256 + tid];
  __syncthreads();
  for (int r = wv; r < NRES; r += 4) {
    float p = 0.f;
#pragma unroll
    for (int j0 = 0; j0 < 4; j0++) {
      int j = lane * 4 + j0;
      p += fmaxf(f[j], 0.f) * rfc1_w[r * 256 + j];
    }
    for (int off = 32; off > 0; off >>= 1) p += __shfl_down(p, off);
    if (lane == 0) {
      float x = p + rfc1_b[r];
      x = fmaxf(x, 0.f);
      x = (x - rbn_rm[r]) * rsqrtf(rbn_rv[r] + EPSV) * rbn_g[r] + rbn_b[r];
      res[r] = x;
    }
  }
  __syncthreads();
  {
    float s = rfc2_b[tid];
#pragma unroll
    for (int r = 0; r < NRES; r++) s += res[r] * rfc2_w[tid * NRES + r];
    f2[tid] = f[tid] + s;
  }
  __syncthreads();
  for (int o = wv; o < NFC1; o += 4) {
    float p = 0.f;
#pragma unroll
    for (int j0 = 0; j0 < 4; j0++) {
      int j = lane * 4 + j0;
      p += f2[j] * fc1_w[o * 256 + j];
    }
    for (int off = 32; off > 0; off >>= 1) p += __shfl_down(p, off);
    if (lane == 0) {
      float x = p + fc1_b[o];
      x = (x - bn1_rm[o]) * rsqrtf(bn1_rv[o] + EPSV) * bn1_g[o] + bn1_b[o];
      x = fmaxf(x, 0.01f * x);
      fcv[o] = x;
    }
  }
  __syncthreads();
  if (tid == 0) {
    float l0 = fc2_b[0], l1 = fc2_b[1];
    for (int o2 = 0; o2 < NFC1; o2++) {
      l0 += fcv[o2] * fc2_w[o2];
      l1 += fcv[o2] * fc2_w[NFC1 + o2];
    }
    float mx = fmaxf(l0, l1);
    float lse = mx + __logf(__expf(l0 - mx) + __expf(l1 - mx));
    logp[b * 2 + 0] = l0 - lse;
    logp[b * 2 + 1] = l1 - lse;
  }
}

// ---------------------------------------------------------------------------
extern "C" void kernel_launch(void* const* d_in, const int* in_sizes, int n_in,
                              void* d_out, int out_size, void* d_ws, size_t ws_size,
                              hipStream_t stream) {
  const int*   input  = (const int*)  d_in[0];
  const float* hx     = (const float*)d_in[1];
  const float* cx     = (const float*)d_in[2];
  const int*   seqlen = (const int*)  d_in[3];
  const float* emb_w  = (const float*)d_in[4];
  const float* W_ih   = (const float*)d_in[5];
  const float* W_hh   = (const float*)d_in[6];
  const float* b_ih   = (const float*)d_in[7];
  const float* b_hh   = (const float*)d_in[8];
  const float* rfc1_w = (const float*)d_in[9];
  const float* rfc1_b = (const float*)d_in[10];
  const float* rbn_g  = (const float*)d_in[11];
  const float* rbn_b  = (const float*)d_in[12];
  const float* rbn_rm = (const float*)d_in[13];
  const float* rbn_rv = (const float*)d_in[14];
  const float* rfc2_w = (const float*)d_in[15];
  const float* rfc2_b = (const float*)d_in[16];
  const float* fc1_w  = (const float*)d_in[17];
  const float* fc1_b  = (const float*)d_in[18];
  const float* bn1_g  = (const float*)d_in[19];
  const float* bn1_b  = (const float*)d_in[20];
  const float* bn1_rm = (const float*)d_in[21];
  const float* bn1_rv = (const float*)d_in[22];
  const float* fc2_w  = (const float*)d_in[23];
  const float* fc2_b  = (const float*)d_in[24];

  char* ws = (char*)d_ws;
  f16*   emb16 = (f16*)(ws);                 // 25,731,584 B
  f16*   wih16 = (f16*)(ws + 25731584);      //    524,288 B
  float* bias  = (float*)(ws + 26255872);    //      4,096 B
  f16*   xgtab = (f16*)(ws + 26259968);      // 102,926,336 B
  float* feat  = (float*)(ws + 129186304);   //     65,536 B

  float* out = (float*)d_out;   // [0,128): logp, [128,16512): hx_f, [16512,32896): cx_f

  k0_convert<<<dim3(NTOKEN), 256, 0, stream>>>(emb_w, W_ih, b_ih, b_hh, emb16, wih16, bias);
  k1_gemm<<<dim3((NTOKEN + 63) / 64, 4), 256, 0, stream>>>(emb16, wih16, bias, xgtab);
  k2_rnn<<<dim3(BB), 1024, 0, stream>>>(input, hx, cx, seqlen, W_hh, xgtab, feat,
                                        out + 128, out + 128 + BB * NHID);
  k3_head<<<dim3(BB), 256, 0, stream>>>(feat, rfc1_w, rfc1_b, rbn_g, rbn_b, rbn_rm, rbn_rv,
                                        rfc2_w, rfc2_b, fc1_w, fc1_b, bn1_g, bn1_b, bn1_rm,
                                        bn1_rv, fc2_w, fc2_b, out);
}